// Round 3
// baseline (516.519 us; speedup 1.0000x reference)
//
#include <hip/hip_runtime.h>
#include <hip/hip_bf16.h>
#include <cstdint>
#include <cstddef>

#define NB      8
#define NPTS    16384
#define NPOINT  128
#define NSAMPLE 32
#define CIN     256
#define CMID    256
#define COUT    256
#define KDIM    259      // 3 + 256
#define KPAD    288      // padded to 9 * 32 for MFMA K-steps
#define XS_STRIDE 296    // bf16 elems; 592B = 37*16 -> 16B-aligned rows
#define HS_STRIDE 264    // bf16 elems; 528B = 33*16 -> 16B-aligned rows

typedef __attribute__((ext_vector_type(8))) short bf16x8;
typedef __attribute__((ext_vector_type(4))) float f32x4;

__device__ __forceinline__ short f2bf(float f) {
  unsigned u = __float_as_uint(f);
  u += 0x7fffu + ((u >> 16) & 1u);
  return (short)(u >> 16);
}

// ---------------- FPS: one block per batch ---------------------------------
// 1024 threads, 16 pts/thread PINNED in VGPRs via asm barrier (the compiler
// otherwise rematerializes the loads from L2 every iteration -- R2's 88-VGPR
// kernel was L2-bound on reloads). One barrier/iter; cross-wave argmax via
// packed-u64 shfl_xor tree over 16 LDS slots.
#define FPS_T 1024
#define FPS_W (FPS_T / 64)     // 16 waves
#define FPS_P (NPTS / FPS_T)   // 16 points per thread

__global__ __launch_bounds__(FPS_T) void fps_kernel(const float* __restrict__ xyz,
                                                    int* __restrict__ inds) {
  const int b = blockIdx.x;
  const int t = threadIdx.x;
  const int lane = t & 63, w = t >> 6;
  const float* xb = xyz + (size_t)b * NPTS * 3;

  float px[FPS_P], py[FPS_P], pz[FPS_P], dist[FPS_P];
#pragma unroll
  for (int i = 0; i < FPS_P; ++i) {
    const int j = t + (i << 10);
    px[i] = xb[j * 3 + 0];
    py[i] = xb[j * 3 + 1];
    pz[i] = xb[j * 3 + 2];
    dist[i] = 1e10f;
  }
  // Opaque barrier: forbids rematerialization of the coordinate loads, forcing
  // them to stay resident in VGPRs across all 128 iterations.
#pragma unroll
  for (int i = 0; i < FPS_P; ++i) {
    asm volatile("" : "+v"(px[i]), "+v"(py[i]), "+v"(pz[i]));
  }

  __shared__ unsigned long long s_pack[2][FPS_W];
  __shared__ float swx[2][FPS_W], swy[2][FPS_W], swz[2][FPS_W];

  int far = 0;
  float cx = xb[0], cy = xb[1], cz = xb[2];

  for (int it = 0; it < NPOINT; ++it) {
    if (t == 0) inds[b * NPOINT + it] = far;
    float best = -1.0f;
    int bi = t;
#pragma unroll
    for (int i = 0; i < FPS_P; ++i) {
      float dx = __fsub_rn(px[i], cx);
      float dy = __fsub_rn(py[i], cy);
      float dz = __fsub_rn(pz[i], cz);
      float d  = __fadd_rn(__fadd_rn(__fmul_rn(dx, dx), __fmul_rn(dy, dy)), __fmul_rn(dz, dz));
      float dm = fminf(dist[i], d);
      dist[i] = dm;
      if (dm > best) { best = dm; bi = t + (i << 10); }  // ascending order -> smallest idx on tie
    }
    // wave argmax (tie -> smaller index)
#pragma unroll
    for (int off = 32; off > 0; off >>= 1) {
      float ov = __shfl_down(best, off, 64);
      int   oi = __shfl_down(bi, off, 64);
      if (ov > best || (ov == best && oi < bi)) { best = ov; bi = oi; }
    }
    const int par = it & 1;
    if (lane == 0) {
      // 50-bit monotone pack: dist(32) | inv_idx(14) | slot(4).
      // dist >= 0 so float-bit order == numeric order; inv_idx makes
      // larger-pack == smaller-index on dist ties (numpy first-max rule).
      s_pack[par][w] = ((unsigned long long)__float_as_uint(best) << 18)
                     | ((unsigned long long)(unsigned)(NPTS - 1 - bi) << 4)
                     | (unsigned long long)w;
      swx[par][w] = xb[bi * 3 + 0];
      swy[par][w] = xb[bi * 3 + 1];
      swz[par][w] = xb[bi * 3 + 2];
    }
    __syncthreads();
    unsigned long long pm = s_pack[par][lane & 15];
#pragma unroll
    for (int off = 8; off > 0; off >>= 1) {
      unsigned long long o = __shfl_xor(pm, off, 64);
      if (o > pm) pm = o;
    }
    const int wi = (int)(pm & 15ull);
    far = (NPTS - 1) - (int)((pm >> 4) & (unsigned long long)(NPTS - 1));
    cx = swx[par][wi]; cy = swy[par][wi]; cz = swz[par][wi];
    // no trailing barrier: next iteration's leaders write the other parity
  }
}

// ---------------- ball query: one wave per centroid, first-32-in-order ----------
__global__ __launch_bounds__(256) void ballq_kernel(const float* __restrict__ xyz,
                                                    const int* __restrict__ inds,
                                                    int* __restrict__ idx) {
  const int gw   = (blockIdx.x * 256 + threadIdx.x) >> 6;  // 0..1023
  const int lane = threadIdx.x & 63;
  const int b = gw >> 7, s = gw & 127;
  const float* xb = xyz + (size_t)b * NPTS * 3;
  const int ind = inds[b * NPOINT + s];
  const float cx = xb[ind * 3 + 0], cy = xb[ind * 3 + 1], cz = xb[ind * 3 + 2];
  int* o = idx + gw * NSAMPLE;
  const float R2 = (float)(0.4 * 0.4);
  int total = 0;
  int first_hit = 0;
  bool have_first = false;
  for (int base = 0; base < NPTS && total < NSAMPLE; base += 64) {
    const int j = base + lane;
    float dx = __fsub_rn(xb[j * 3 + 0], cx);
    float dy = __fsub_rn(xb[j * 3 + 1], cy);
    float dz = __fsub_rn(xb[j * 3 + 2], cz);
    float d2 = __fadd_rn(__fadd_rn(__fmul_rn(dx, dx), __fmul_rn(dy, dy)), __fmul_rn(dz, dz));
    bool hit = d2 < R2;
    unsigned long long m = __ballot(hit);
    if (!have_first && m) { first_hit = base + (int)__builtin_ctzll(m); have_first = true; }
    int pos = total + (int)__popcll(m & ((1ull << lane) - 1ull));
    if (hit && pos < NSAMPLE) o[pos] = j;
    total += (int)__popcll(m);
  }
  for (int p = total + lane; p < NSAMPLE; p += 64) o[p] = first_hit;  // pad w/ first hit
}

// ---------------- prep: fold BN into bf16 weights + fp32 bias -------------------
__global__ __launch_bounds__(256) void prep_kernel(
    const float* __restrict__ w1, const float* __restrict__ g1, const float* __restrict__ be1,
    const float* __restrict__ m1, const float* __restrict__ v1,
    const float* __restrict__ w2, const float* __restrict__ g2, const float* __restrict__ be2,
    const float* __restrict__ m2, const float* __restrict__ v2,
    short* __restrict__ w1b, short* __restrict__ w2b,
    float* __restrict__ b1, float* __restrict__ b2) {
  int i = blockIdx.x * 256 + threadIdx.x;
  if (i < CMID * KPAD) {
    int oc = i / KPAD, c = i - oc * KPAD;
    float a = g1[oc] * rsqrtf(v1[oc] + 1e-5f);
    float val = (c < KDIM) ? w1[oc * KDIM + c] * a : 0.0f;
    w1b[i] = f2bf(val);
    if (c == 0) b1[oc] = be1[oc] - m1[oc] * a;
  }
  if (i < COUT * CMID) {
    int oc = i >> 8, c = i & 255;
    float a = g2[oc] * rsqrtf(v2[oc] + 1e-5f);
    w2b[i] = f2bf(w2[oc * CMID + c] * a);
    if (c == 0) b2[oc] = be2[oc] - m2[oc] * a;
  }
}

// ---------------- fused gather + MLP(2 layers) + maxpool ------------------------
__global__ __launch_bounds__(256) void mlp_kernel(
    const float* __restrict__ xyz, const float* __restrict__ feats,
    const int* __restrict__ inds, const int* __restrict__ idx,
    const short* __restrict__ w1b, const short* __restrict__ w2b,
    const float* __restrict__ b1, const float* __restrict__ b2,
    float* __restrict__ out) {
  const int g   = blockIdx.x;           // b*128 + s
  const int bb  = g >> 7, s = g & 127;
  const int tid = threadIdx.x;
  const int wave = tid >> 6, lane = tid & 63;
  const int lrow = lane & 15, quad = lane >> 4;

  __shared__ short Xs[32 * XS_STRIDE];
  __shared__ short Hs[32 * HS_STRIDE];
  __shared__ int   sj[NSAMPLE];
  __shared__ float scen[3];

  if (tid < NSAMPLE) sj[tid] = idx[g * NSAMPLE + tid];
  if (tid < 3) {
    int ind = inds[bb * NPOINT + s];
    scen[tid] = xyz[((size_t)bb * NPTS + ind) * 3 + tid];
  }
  __syncthreads();

  // gather [32 rows x 288] into LDS as bf16 (pad channels 259..287 = 0)
  for (int e = tid; e < 32 * KPAD; e += 256) {
    int r = e / KPAD, c = e - r * KPAD;
    int j = sj[r];
    float val;
    if (c < 3)          val = xyz[((size_t)bb * NPTS + j) * 3 + c] - scen[c];
    else if (c < KDIM)  val = feats[((size_t)bb * NPTS + j) * CIN + (c - 3)];
    else                val = 0.0f;
    Xs[r * XS_STRIDE + c] = f2bf(val);
  }
  __syncthreads();

  const int nw = wave * 64;   // this wave's output-channel base
  f32x4 acc[4][2];
#pragma unroll
  for (int nt = 0; nt < 4; ++nt)
#pragma unroll
    for (int mt = 0; mt < 2; ++mt) acc[nt][mt] = (f32x4){0.f, 0.f, 0.f, 0.f};

  // GEMM1: [32 x 288] @ W1^T -> [32 x 256]
  for (int ks = 0; ks < 9; ++ks) {
    const int ko = ks * 32 + quad * 8;
    bf16x8 a0 = *(const bf16x8*)(&Xs[lrow * XS_STRIDE + ko]);
    bf16x8 a1 = *(const bf16x8*)(&Xs[(lrow + 16) * XS_STRIDE + ko]);
#pragma unroll
    for (int nt = 0; nt < 4; ++nt) {
      const int oc = nw + nt * 16 + lrow;
      bf16x8 bf = *(const bf16x8*)(w1b + oc * KPAD + ko);
      acc[nt][0] = __builtin_amdgcn_mfma_f32_16x16x32_bf16(a0, bf, acc[nt][0], 0, 0, 0);
      acc[nt][1] = __builtin_amdgcn_mfma_f32_16x16x32_bf16(a1, bf, acc[nt][1], 0, 0, 0);
    }
  }

  // epilogue1: bias + relu -> Hs (bf16). C/D layout: col=lane&15, row=quad*4+reg
#pragma unroll
  for (int nt = 0; nt < 4; ++nt) {
    const int oc = nw + nt * 16 + lrow;
    const float bias = b1[oc];
#pragma unroll
    for (int mt = 0; mt < 2; ++mt) {
#pragma unroll
      for (int r = 0; r < 4; ++r) {
        int row = mt * 16 + quad * 4 + r;
        float h = fmaxf(acc[nt][mt][r] + bias, 0.0f);
        Hs[row * HS_STRIDE + oc] = f2bf(h);
      }
    }
  }
  __syncthreads();

#pragma unroll
  for (int nt = 0; nt < 4; ++nt)
#pragma unroll
    for (int mt = 0; mt < 2; ++mt) acc[nt][mt] = (f32x4){0.f, 0.f, 0.f, 0.f};

  // GEMM2: [32 x 256] @ W2^T -> [32 x 256]
  for (int ks = 0; ks < 8; ++ks) {
    const int ko = ks * 32 + quad * 8;
    bf16x8 a0 = *(const bf16x8*)(&Hs[lrow * HS_STRIDE + ko]);
    bf16x8 a1 = *(const bf16x8*)(&Hs[(lrow + 16) * HS_STRIDE + ko]);
#pragma unroll
    for (int nt = 0; nt < 4; ++nt) {
      const int oc = nw + nt * 16 + lrow;
      bf16x8 bf = *(const bf16x8*)(w2b + oc * CMID + ko);
      acc[nt][0] = __builtin_amdgcn_mfma_f32_16x16x32_bf16(a0, bf, acc[nt][0], 0, 0, 0);
      acc[nt][1] = __builtin_amdgcn_mfma_f32_16x16x32_bf16(a1, bf, acc[nt][1], 0, 0, 0);
    }
  }

  // epilogue2: bias + relu + max over 32 samples -> out[b][oc][s]
#pragma unroll
  for (int nt = 0; nt < 4; ++nt) {
    const int oc = nw + nt * 16 + lrow;
    const float bias = b2[oc];
    float v = -3.4e38f;
#pragma unroll
    for (int mt = 0; mt < 2; ++mt) {
      f32x4 a = acc[nt][mt];
      v = fmaxf(v, fmaxf(fmaxf(a[0], a[1]), fmaxf(a[2], a[3])));
    }
    v = fmaxf(v + bias, 0.0f);            // monotone: == max of per-element bias+relu
    v = fmaxf(v, __shfl_xor(v, 16, 64));
    v = fmaxf(v, __shfl_xor(v, 32, 64));
    if (lane < 16) out[((size_t)bb * COUT + oc) * NPOINT + s] = v;
  }
}

extern "C" void kernel_launch(void* const* d_in, const int* in_sizes, int n_in,
                              void* d_out, int out_size, void* d_ws, size_t ws_size,
                              hipStream_t stream) {
  const float* xyz   = (const float*)d_in[0];
  const float* feats = (const float*)d_in[1];
  const float* w1    = (const float*)d_in[2];
  const float* g1    = (const float*)d_in[3];
  const float* be1   = (const float*)d_in[4];
  const float* m1    = (const float*)d_in[5];
  const float* v1    = (const float*)d_in[6];
  const float* w2    = (const float*)d_in[7];
  const float* g2    = (const float*)d_in[8];
  const float* be2   = (const float*)d_in[9];
  const float* m2    = (const float*)d_in[10];
  const float* v2    = (const float*)d_in[11];
  float* out = (float*)d_out;

  char* ws = (char*)d_ws;
  int*   inds = (int*)(ws);              // 1024 ints   -> 4096 B
  int*   idx  = (int*)(ws + 4096);       // 32768 ints  -> 131072 B
  short* w1b  = (short*)(ws + 135168);   // 256*288 bf16 -> 147456 B
  short* w2b  = (short*)(ws + 282624);   // 256*256 bf16 -> 131072 B
  float* b1   = (float*)(ws + 413696);   // 256 f32
  float* b2   = (float*)(ws + 414720);   // 256 f32

  prep_kernel<<<288, 256, 0, stream>>>(w1, g1, be1, m1, v1, w2, g2, be2, m2, v2,
                                       w1b, w2b, b1, b2);
  fps_kernel<<<NB, FPS_T, 0, stream>>>(xyz, inds);
  ballq_kernel<<<256, 256, 0, stream>>>(xyz, inds, idx);
  mlp_kernel<<<NB * NPOINT, 256, 0, stream>>>(xyz, feats, inds, idx, w1b, w2b, b1, b2, out);
}

// Round 4
// 490.083 us; speedup vs baseline: 1.0539x; 1.0539x over previous
//
#include <hip/hip_runtime.h>
#include <hip/hip_bf16.h>
#include <cstdint>
#include <cstddef>

#define NB      8
#define NPTS    16384
#define NPOINT  128
#define NSAMPLE 32
#define CIN     256
#define CMID    256
#define COUT    256
#define KDIM    259      // 3 + 256
#define KPAD    288      // padded to 9 * 32 for MFMA K-steps
#define XS_STRIDE 296    // bf16 elems; 592B = 37*16 -> 16B-aligned rows
#define HS_STRIDE 264    // bf16 elems; 528B = 33*16 -> 16B-aligned rows

typedef __attribute__((ext_vector_type(8))) short bf16x8;
typedef __attribute__((ext_vector_type(4))) float f32x4;

__device__ __forceinline__ short f2bf(float f) {
  unsigned u = __float_as_uint(f);
  u += 0x7fffu + ((u >> 16) & 1u);
  return (short)(u >> 16);
}

// ---------------- FPS: one block per batch ---------------------------------
// 512 threads x 32 pts/thread, coords+dist PINNED in VGPRs:
//  - asm barrier forbids rematerialization (R2 failure mode: 88 VGPRs, remat
//    reloads from L2 every iter),
//  - __launch_bounds__(512, 2) sets a 256-VGPR budget so the allocator does
//    not spill the pinned values to scratch (R3 failure mode: 64-reg budget
//    from the default 1024-thread occupancy heuristic -> scratch spill,
//    ~330 KB/iter through L2, 5200 cyc/iter).
// Need ~160 VGPRs (96 coord + 32 dist + temps) < 256.
#define FPS_T 512
#define FPS_W (FPS_T / 64)     // 8 waves
#define FPS_P (NPTS / FPS_T)   // 32 points per thread

__global__ __launch_bounds__(FPS_T, 2) void fps_kernel(const float* __restrict__ xyz,
                                                       int* __restrict__ inds) {
  const int b = blockIdx.x;
  const int t = threadIdx.x;
  const int lane = t & 63, w = t >> 6;
  const float* xb = xyz + (size_t)b * NPTS * 3;

  float px[FPS_P], py[FPS_P], pz[FPS_P], dist[FPS_P];
#pragma unroll
  for (int i = 0; i < FPS_P; ++i) {
    const int j = t + i * FPS_T;
    px[i] = xb[j * 3 + 0];
    py[i] = xb[j * 3 + 1];
    pz[i] = xb[j * 3 + 2];
    dist[i] = 1e10f;
  }
  // Opaque barrier: values become asm outputs, so reloading from global is
  // illegal; with the 256-reg budget they stay VGPR-resident.
#pragma unroll
  for (int i = 0; i < FPS_P; ++i) {
    asm volatile("" : "+v"(px[i]), "+v"(py[i]), "+v"(pz[i]));
  }

  __shared__ unsigned long long s_pack[2][FPS_W];
  __shared__ float swx[2][FPS_W], swy[2][FPS_W], swz[2][FPS_W];

  int far = 0;
  float cx = xb[0], cy = xb[1], cz = xb[2];

  for (int it = 0; it < NPOINT; ++it) {
    if (t == 0) inds[b * NPOINT + it] = far;
    float best = -1.0f;
    int bi = t;
#pragma unroll
    for (int i = 0; i < FPS_P; ++i) {
      float dx = __fsub_rn(px[i], cx);
      float dy = __fsub_rn(py[i], cy);
      float dz = __fsub_rn(pz[i], cz);
      float d  = __fadd_rn(__fadd_rn(__fmul_rn(dx, dx), __fmul_rn(dy, dy)), __fmul_rn(dz, dz));
      float dm = fminf(dist[i], d);
      dist[i] = dm;
      if (dm > best) { best = dm; bi = t + i * FPS_T; }  // ascending order -> smallest idx on tie
    }
    // wave argmax (tie -> smaller index)
#pragma unroll
    for (int off = 32; off > 0; off >>= 1) {
      float ov = __shfl_down(best, off, 64);
      int   oi = __shfl_down(bi, off, 64);
      if (ov > best || (ov == best && oi < bi)) { best = ov; bi = oi; }
    }
    const int par = it & 1;
    if (lane == 0) {
      // 49-bit monotone pack: dist(32) | inv_idx(14) | slot(3).
      // dist >= 0 so float-bit order == numeric order; inv_idx makes
      // larger-pack == smaller-index on dist ties (numpy first-max rule).
      s_pack[par][w] = ((unsigned long long)__float_as_uint(best) << 17)
                     | ((unsigned long long)(unsigned)(NPTS - 1 - bi) << 3)
                     | (unsigned long long)w;
      swx[par][w] = xb[bi * 3 + 0];
      swy[par][w] = xb[bi * 3 + 1];
      swz[par][w] = xb[bi * 3 + 2];
    }
    __syncthreads();
    unsigned long long pm = s_pack[par][lane & 7];
#pragma unroll
    for (int off = 4; off > 0; off >>= 1) {
      unsigned long long o = __shfl_xor(pm, off, 64);
      if (o > pm) pm = o;
    }
    const int wi = (int)(pm & 7ull);
    far = (NPTS - 1) - (int)((pm >> 3) & (unsigned long long)(NPTS - 1));
    cx = swx[par][wi]; cy = swy[par][wi]; cz = swz[par][wi];
    // no trailing barrier: next iteration's leaders write the other parity
  }
}

// ---------------- ball query: one wave per centroid, first-32-in-order ----------
__global__ __launch_bounds__(256) void ballq_kernel(const float* __restrict__ xyz,
                                                    const int* __restrict__ inds,
                                                    int* __restrict__ idx) {
  const int gw   = (blockIdx.x * 256 + threadIdx.x) >> 6;  // 0..1023
  const int lane = threadIdx.x & 63;
  const int b = gw >> 7, s = gw & 127;
  const float* xb = xyz + (size_t)b * NPTS * 3;
  const int ind = inds[b * NPOINT + s];
  const float cx = xb[ind * 3 + 0], cy = xb[ind * 3 + 1], cz = xb[ind * 3 + 2];
  int* o = idx + gw * NSAMPLE;
  const float R2 = (float)(0.4 * 0.4);
  int total = 0;
  int first_hit = 0;
  bool have_first = false;
  for (int base = 0; base < NPTS && total < NSAMPLE; base += 64) {
    const int j = base + lane;
    float dx = __fsub_rn(xb[j * 3 + 0], cx);
    float dy = __fsub_rn(xb[j * 3 + 1], cy);
    float dz = __fsub_rn(xb[j * 3 + 2], cz);
    float d2 = __fadd_rn(__fadd_rn(__fmul_rn(dx, dx), __fmul_rn(dy, dy)), __fmul_rn(dz, dz));
    bool hit = d2 < R2;
    unsigned long long m = __ballot(hit);
    if (!have_first && m) { first_hit = base + (int)__builtin_ctzll(m); have_first = true; }
    int pos = total + (int)__popcll(m & ((1ull << lane) - 1ull));
    if (hit && pos < NSAMPLE) o[pos] = j;
    total += (int)__popcll(m);
  }
  for (int p = total + lane; p < NSAMPLE; p += 64) o[p] = first_hit;  // pad w/ first hit
}

// ---------------- prep: fold BN into bf16 weights + fp32 bias -------------------
__global__ __launch_bounds__(256) void prep_kernel(
    const float* __restrict__ w1, const float* __restrict__ g1, const float* __restrict__ be1,
    const float* __restrict__ m1, const float* __restrict__ v1,
    const float* __restrict__ w2, const float* __restrict__ g2, const float* __restrict__ be2,
    const float* __restrict__ m2, const float* __restrict__ v2,
    short* __restrict__ w1b, short* __restrict__ w2b,
    float* __restrict__ b1, float* __restrict__ b2) {
  int i = blockIdx.x * 256 + threadIdx.x;
  if (i < CMID * KPAD) {
    int oc = i / KPAD, c = i - oc * KPAD;
    float a = g1[oc] * rsqrtf(v1[oc] + 1e-5f);
    float val = (c < KDIM) ? w1[oc * KDIM + c] * a : 0.0f;
    w1b[i] = f2bf(val);
    if (c == 0) b1[oc] = be1[oc] - m1[oc] * a;
  }
  if (i < COUT * CMID) {
    int oc = i >> 8, c = i & 255;
    float a = g2[oc] * rsqrtf(v2[oc] + 1e-5f);
    w2b[i] = f2bf(w2[oc * CMID + c] * a);
    if (c == 0) b2[oc] = be2[oc] - m2[oc] * a;
  }
}

// ---------------- fused gather + MLP(2 layers) + maxpool ------------------------
__global__ __launch_bounds__(256) void mlp_kernel(
    const float* __restrict__ xyz, const float* __restrict__ feats,
    const int* __restrict__ inds, const int* __restrict__ idx,
    const short* __restrict__ w1b, const short* __restrict__ w2b,
    const float* __restrict__ b1, const float* __restrict__ b2,
    float* __restrict__ out) {
  const int g   = blockIdx.x;           // b*128 + s
  const int bb  = g >> 7, s = g & 127;
  const int tid = threadIdx.x;
  const int wave = tid >> 6, lane = tid & 63;
  const int lrow = lane & 15, quad = lane >> 4;

  __shared__ short Xs[32 * XS_STRIDE];
  __shared__ short Hs[32 * HS_STRIDE];
  __shared__ int   sj[NSAMPLE];
  __shared__ float scen[3];

  if (tid < NSAMPLE) sj[tid] = idx[g * NSAMPLE + tid];
  if (tid < 3) {
    int ind = inds[bb * NPOINT + s];
    scen[tid] = xyz[((size_t)bb * NPTS + ind) * 3 + tid];
  }
  __syncthreads();

  // gather [32 rows x 288] into LDS as bf16 (pad channels 259..287 = 0)
  for (int e = tid; e < 32 * KPAD; e += 256) {
    int r = e / KPAD, c = e - r * KPAD;
    int j = sj[r];
    float val;
    if (c < 3)          val = xyz[((size_t)bb * NPTS + j) * 3 + c] - scen[c];
    else if (c < KDIM)  val = feats[((size_t)bb * NPTS + j) * CIN + (c - 3)];
    else                val = 0.0f;
    Xs[r * XS_STRIDE + c] = f2bf(val);
  }
  __syncthreads();

  const int nw = wave * 64;   // this wave's output-channel base
  f32x4 acc[4][2];
#pragma unroll
  for (int nt = 0; nt < 4; ++nt)
#pragma unroll
    for (int mt = 0; mt < 2; ++mt) acc[nt][mt] = (f32x4){0.f, 0.f, 0.f, 0.f};

  // GEMM1: [32 x 288] @ W1^T -> [32 x 256]
  for (int ks = 0; ks < 9; ++ks) {
    const int ko = ks * 32 + quad * 8;
    bf16x8 a0 = *(const bf16x8*)(&Xs[lrow * XS_STRIDE + ko]);
    bf16x8 a1 = *(const bf16x8*)(&Xs[(lrow + 16) * XS_STRIDE + ko]);
#pragma unroll
    for (int nt = 0; nt < 4; ++nt) {
      const int oc = nw + nt * 16 + lrow;
      bf16x8 bf = *(const bf16x8*)(w1b + oc * KPAD + ko);
      acc[nt][0] = __builtin_amdgcn_mfma_f32_16x16x32_bf16(a0, bf, acc[nt][0], 0, 0, 0);
      acc[nt][1] = __builtin_amdgcn_mfma_f32_16x16x32_bf16(a1, bf, acc[nt][1], 0, 0, 0);
    }
  }

  // epilogue1: bias + relu -> Hs (bf16). C/D layout: col=lane&15, row=quad*4+reg
#pragma unroll
  for (int nt = 0; nt < 4; ++nt) {
    const int oc = nw + nt * 16 + lrow;
    const float bias = b1[oc];
#pragma unroll
    for (int mt = 0; mt < 2; ++mt) {
#pragma unroll
      for (int r = 0; r < 4; ++r) {
        int row = mt * 16 + quad * 4 + r;
        float h = fmaxf(acc[nt][mt][r] + bias, 0.0f);
        Hs[row * HS_STRIDE + oc] = f2bf(h);
      }
    }
  }
  __syncthreads();

#pragma unroll
  for (int nt = 0; nt < 4; ++nt)
#pragma unroll
    for (int mt = 0; mt < 2; ++mt) acc[nt][mt] = (f32x4){0.f, 0.f, 0.f, 0.f};

  // GEMM2: [32 x 256] @ W2^T -> [32 x 256]
  for (int ks = 0; ks < 8; ++ks) {
    const int ko = ks * 32 + quad * 8;
    bf16x8 a0 = *(const bf16x8*)(&Hs[lrow * HS_STRIDE + ko]);
    bf16x8 a1 = *(const bf16x8*)(&Hs[(lrow + 16) * HS_STRIDE + ko]);
#pragma unroll
    for (int nt = 0; nt < 4; ++nt) {
      const int oc = nw + nt * 16 + lrow;
      bf16x8 bf = *(const bf16x8*)(w2b + oc * CMID + ko);
      acc[nt][0] = __builtin_amdgcn_mfma_f32_16x16x32_bf16(a0, bf, acc[nt][0], 0, 0, 0);
      acc[nt][1] = __builtin_amdgcn_mfma_f32_16x16x32_bf16(a1, bf, acc[nt][1], 0, 0, 0);
    }
  }

  // epilogue2: bias + relu + max over 32 samples -> out[b][oc][s]
#pragma unroll
  for (int nt = 0; nt < 4; ++nt) {
    const int oc = nw + nt * 16 + lrow;
    const float bias = b2[oc];
    float v = -3.4e38f;
#pragma unroll
    for (int mt = 0; mt < 2; ++mt) {
      f32x4 a = acc[nt][mt];
      v = fmaxf(v, fmaxf(fmaxf(a[0], a[1]), fmaxf(a[2], a[3])));
    }
    v = fmaxf(v + bias, 0.0f);            // monotone: == max of per-element bias+relu
    v = fmaxf(v, __shfl_xor(v, 16, 64));
    v = fmaxf(v, __shfl_xor(v, 32, 64));
    if (lane < 16) out[((size_t)bb * COUT + oc) * NPOINT + s] = v;
  }
}

extern "C" void kernel_launch(void* const* d_in, const int* in_sizes, int n_in,
                              void* d_out, int out_size, void* d_ws, size_t ws_size,
                              hipStream_t stream) {
  const float* xyz   = (const float*)d_in[0];
  const float* feats = (const float*)d_in[1];
  const float* w1    = (const float*)d_in[2];
  const float* g1    = (const float*)d_in[3];
  const float* be1   = (const float*)d_in[4];
  const float* m1    = (const float*)d_in[5];
  const float* v1    = (const float*)d_in[6];
  const float* w2    = (const float*)d_in[7];
  const float* g2    = (const float*)d_in[8];
  const float* be2   = (const float*)d_in[9];
  const float* m2    = (const float*)d_in[10];
  const float* v2    = (const float*)d_in[11];
  float* out = (float*)d_out;

  char* ws = (char*)d_ws;
  int*   inds = (int*)(ws);              // 1024 ints   -> 4096 B
  int*   idx  = (int*)(ws + 4096);       // 32768 ints  -> 131072 B
  short* w1b  = (short*)(ws + 135168);   // 256*288 bf16 -> 147456 B
  short* w2b  = (short*)(ws + 282624);   // 256*256 bf16 -> 131072 B
  float* b1   = (float*)(ws + 413696);   // 256 f32
  float* b2   = (float*)(ws + 414720);   // 256 f32

  prep_kernel<<<288, 256, 0, stream>>>(w1, g1, be1, m1, v1, w2, g2, be2, m2, v2,
                                       w1b, w2b, b1, b2);
  fps_kernel<<<NB, FPS_T, 0, stream>>>(xyz, inds);
  ballq_kernel<<<256, 256, 0, stream>>>(xyz, inds, idx);
  mlp_kernel<<<NB * NPOINT, 256, 0, stream>>>(xyz, feats, inds, idx, w1b, w2b, b1, b2, out);
}

// Round 5
// 489.125 us; speedup vs baseline: 1.0560x; 1.0020x over previous
//
#include <hip/hip_runtime.h>
#include <hip/hip_bf16.h>
#include <cstdint>
#include <cstddef>

#define NB      8
#define NPTS    16384
#define NPOINT  128
#define NSAMPLE 32
#define CIN     256
#define CMID    256
#define COUT    256
#define KDIM    259      // 3 + 256
#define KPAD    288      // padded to 9 * 32 for MFMA K-steps
#define XS_STRIDE 296    // bf16 elems; 592B = 37*16 -> 16B-aligned rows
#define HS_STRIDE 264    // bf16 elems; 528B = 33*16 -> 16B-aligned rows

typedef __attribute__((ext_vector_type(8))) short bf16x8;
typedef __attribute__((ext_vector_type(4))) float f32x4;

__device__ __forceinline__ short f2bf(float f) {
  unsigned u = __float_as_uint(f);
  u += 0x7fffu + ((u >> 16) & 1u);
  return (short)(u >> 16);
}

// ---------------- FPS: one block per batch ---------------------------------
// 512 threads x 32 pts/thread, coords+dist held in VGPRs. Three knobs, all
// required (each round removed one failure mode):
//  - asm barrier: forbids rematerialization from global (R2: 88 VGPR, L2
//    reloads every iter).
//  - 256-VGPR budget: R3's 1024-thr default budget (64) forced scratch spill.
//  - amdgpu_waves_per_eu(2,2): R4 showed min-occupancy alone lets the
//    scheduler TARGET 6 waves/EU (512/6 = 84 VGPR) and spill the pinned
//    values to scratch anyway. Pinning the range to exactly 2 makes the
//    256-reg budget the allocation target. Need ~160 regs (96+32+temps).
#define FPS_T 512
#define FPS_W (FPS_T / 64)     // 8 waves
#define FPS_P (NPTS / FPS_T)   // 32 points per thread

__global__ __launch_bounds__(FPS_T) __attribute__((amdgpu_waves_per_eu(2, 2)))
void fps_kernel(const float* __restrict__ xyz, int* __restrict__ inds) {
  const int b = blockIdx.x;
  const int t = threadIdx.x;
  const int lane = t & 63, w = t >> 6;
  const float* xb = xyz + (size_t)b * NPTS * 3;

  float px[FPS_P], py[FPS_P], pz[FPS_P], dist[FPS_P];
#pragma unroll
  for (int i = 0; i < FPS_P; ++i) {
    const int j = t + i * FPS_T;
    px[i] = xb[j * 3 + 0];
    py[i] = xb[j * 3 + 1];
    pz[i] = xb[j * 3 + 2];
    dist[i] = 1e10f;
  }
  // Opaque barrier: values become asm results, so reloading from global is
  // illegal; with the pinned occupancy range they stay VGPR-resident.
#pragma unroll
  for (int i = 0; i < FPS_P; ++i) {
    asm volatile("" : "+v"(px[i]), "+v"(py[i]), "+v"(pz[i]));
  }

  __shared__ unsigned long long s_pack[2][FPS_W];
  __shared__ float swx[2][FPS_W], swy[2][FPS_W], swz[2][FPS_W];

  int far = 0;
  float cx = xb[0], cy = xb[1], cz = xb[2];

  for (int it = 0; it < NPOINT; ++it) {
    if (t == 0) inds[b * NPOINT + it] = far;
    float best = -1.0f;
    int bi = t;
#pragma unroll
    for (int i = 0; i < FPS_P; ++i) {
      float dx = __fsub_rn(px[i], cx);
      float dy = __fsub_rn(py[i], cy);
      float dz = __fsub_rn(pz[i], cz);
      float d  = __fadd_rn(__fadd_rn(__fmul_rn(dx, dx), __fmul_rn(dy, dy)), __fmul_rn(dz, dz));
      float dm = fminf(dist[i], d);
      dist[i] = dm;
      if (dm > best) { best = dm; bi = t + i * FPS_T; }  // ascending order -> smallest idx on tie
    }
    // wave argmax (tie -> smaller index)
#pragma unroll
    for (int off = 32; off > 0; off >>= 1) {
      float ov = __shfl_down(best, off, 64);
      int   oi = __shfl_down(bi, off, 64);
      if (ov > best || (ov == best && oi < bi)) { best = ov; bi = oi; }
    }
    const int par = it & 1;
    if (lane == 0) {
      // 49-bit monotone pack: dist(32) | inv_idx(14) | slot(3).
      // dist >= 0 so float-bit order == numeric order; inv_idx makes
      // larger-pack == smaller-index on dist ties (numpy first-max rule).
      s_pack[par][w] = ((unsigned long long)__float_as_uint(best) << 17)
                     | ((unsigned long long)(unsigned)(NPTS - 1 - bi) << 3)
                     | (unsigned long long)w;
      swx[par][w] = xb[bi * 3 + 0];
      swy[par][w] = xb[bi * 3 + 1];
      swz[par][w] = xb[bi * 3 + 2];
    }
    __syncthreads();
    unsigned long long pm = s_pack[par][lane & 7];
#pragma unroll
    for (int off = 4; off > 0; off >>= 1) {
      unsigned long long o = __shfl_xor(pm, off, 64);
      if (o > pm) pm = o;
    }
    const int wi = (int)(pm & 7ull);
    far = (NPTS - 1) - (int)((pm >> 3) & (unsigned long long)(NPTS - 1));
    cx = swx[par][wi]; cy = swy[par][wi]; cz = swz[par][wi];
    // no trailing barrier: next iteration's leaders write the other parity
  }
}

// ---------------- ball query: one wave per centroid, first-32-in-order ----------
__global__ __launch_bounds__(256) void ballq_kernel(const float* __restrict__ xyz,
                                                    const int* __restrict__ inds,
                                                    int* __restrict__ idx) {
  const int gw   = (blockIdx.x * 256 + threadIdx.x) >> 6;  // 0..1023
  const int lane = threadIdx.x & 63;
  const int b = gw >> 7, s = gw & 127;
  const float* xb = xyz + (size_t)b * NPTS * 3;
  const int ind = inds[b * NPOINT + s];
  const float cx = xb[ind * 3 + 0], cy = xb[ind * 3 + 1], cz = xb[ind * 3 + 2];
  int* o = idx + gw * NSAMPLE;
  const float R2 = (float)(0.4 * 0.4);
  int total = 0;
  int first_hit = 0;
  bool have_first = false;
  for (int base = 0; base < NPTS && total < NSAMPLE; base += 64) {
    const int j = base + lane;
    float dx = __fsub_rn(xb[j * 3 + 0], cx);
    float dy = __fsub_rn(xb[j * 3 + 1], cy);
    float dz = __fsub_rn(xb[j * 3 + 2], cz);
    float d2 = __fadd_rn(__fadd_rn(__fmul_rn(dx, dx), __fmul_rn(dy, dy)), __fmul_rn(dz, dz));
    bool hit = d2 < R2;
    unsigned long long m = __ballot(hit);
    if (!have_first && m) { first_hit = base + (int)__builtin_ctzll(m); have_first = true; }
    int pos = total + (int)__popcll(m & ((1ull << lane) - 1ull));
    if (hit && pos < NSAMPLE) o[pos] = j;
    total += (int)__popcll(m);
  }
  for (int p = total + lane; p < NSAMPLE; p += 64) o[p] = first_hit;  // pad w/ first hit
}

// ---------------- prep: fold BN into bf16 weights + fp32 bias -------------------
__global__ __launch_bounds__(256) void prep_kernel(
    const float* __restrict__ w1, const float* __restrict__ g1, const float* __restrict__ be1,
    const float* __restrict__ m1, const float* __restrict__ v1,
    const float* __restrict__ w2, const float* __restrict__ g2, const float* __restrict__ be2,
    const float* __restrict__ m2, const float* __restrict__ v2,
    short* __restrict__ w1b, short* __restrict__ w2b,
    float* __restrict__ b1, float* __restrict__ b2) {
  int i = blockIdx.x * 256 + threadIdx.x;
  if (i < CMID * KPAD) {
    int oc = i / KPAD, c = i - oc * KPAD;
    float a = g1[oc] * rsqrtf(v1[oc] + 1e-5f);
    float val = (c < KDIM) ? w1[oc * KDIM + c] * a : 0.0f;
    w1b[i] = f2bf(val);
    if (c == 0) b1[oc] = be1[oc] - m1[oc] * a;
  }
  if (i < COUT * CMID) {
    int oc = i >> 8, c = i & 255;
    float a = g2[oc] * rsqrtf(v2[oc] + 1e-5f);
    w2b[i] = f2bf(w2[oc * CMID + c] * a);
    if (c == 0) b2[oc] = be2[oc] - m2[oc] * a;
  }
}

// ---------------- fused gather + MLP(2 layers) + maxpool ------------------------
__global__ __launch_bounds__(256) void mlp_kernel(
    const float* __restrict__ xyz, const float* __restrict__ feats,
    const int* __restrict__ inds, const int* __restrict__ idx,
    const short* __restrict__ w1b, const short* __restrict__ w2b,
    const float* __restrict__ b1, const float* __restrict__ b2,
    float* __restrict__ out) {
  const int g   = blockIdx.x;           // b*128 + s
  const int bb  = g >> 7, s = g & 127;
  const int tid = threadIdx.x;
  const int wave = tid >> 6, lane = tid & 63;
  const int lrow = lane & 15, quad = lane >> 4;

  __shared__ short Xs[32 * XS_STRIDE];
  __shared__ short Hs[32 * HS_STRIDE];
  __shared__ int   sj[NSAMPLE];
  __shared__ float scen[3];

  if (tid < NSAMPLE) sj[tid] = idx[g * NSAMPLE + tid];
  if (tid < 3) {
    int ind = inds[bb * NPOINT + s];
    scen[tid] = xyz[((size_t)bb * NPTS + ind) * 3 + tid];
  }
  __syncthreads();

  // gather [32 rows x 288] into LDS as bf16 (pad channels 259..287 = 0)
  for (int e = tid; e < 32 * KPAD; e += 256) {
    int r = e / KPAD, c = e - r * KPAD;
    int j = sj[r];
    float val;
    if (c < 3)          val = xyz[((size_t)bb * NPTS + j) * 3 + c] - scen[c];
    else if (c < KDIM)  val = feats[((size_t)bb * NPTS + j) * CIN + (c - 3)];
    else                val = 0.0f;
    Xs[r * XS_STRIDE + c] = f2bf(val);
  }
  __syncthreads();

  const int nw = wave * 64;   // this wave's output-channel base
  f32x4 acc[4][2];
#pragma unroll
  for (int nt = 0; nt < 4; ++nt)
#pragma unroll
    for (int mt = 0; mt < 2; ++mt) acc[nt][mt] = (f32x4){0.f, 0.f, 0.f, 0.f};

  // GEMM1: [32 x 288] @ W1^T -> [32 x 256]
  for (int ks = 0; ks < 9; ++ks) {
    const int ko = ks * 32 + quad * 8;
    bf16x8 a0 = *(const bf16x8*)(&Xs[lrow * XS_STRIDE + ko]);
    bf16x8 a1 = *(const bf16x8*)(&Xs[(lrow + 16) * XS_STRIDE + ko]);
#pragma unroll
    for (int nt = 0; nt < 4; ++nt) {
      const int oc = nw + nt * 16 + lrow;
      bf16x8 bf = *(const bf16x8*)(w1b + oc * KPAD + ko);
      acc[nt][0] = __builtin_amdgcn_mfma_f32_16x16x32_bf16(a0, bf, acc[nt][0], 0, 0, 0);
      acc[nt][1] = __builtin_amdgcn_mfma_f32_16x16x32_bf16(a1, bf, acc[nt][1], 0, 0, 0);
    }
  }

  // epilogue1: bias + relu -> Hs (bf16). C/D layout: col=lane&15, row=quad*4+reg
#pragma unroll
  for (int nt = 0; nt < 4; ++nt) {
    const int oc = nw + nt * 16 + lrow;
    const float bias = b1[oc];
#pragma unroll
    for (int mt = 0; mt < 2; ++mt) {
#pragma unroll
      for (int r = 0; r < 4; ++r) {
        int row = mt * 16 + quad * 4 + r;
        float h = fmaxf(acc[nt][mt][r] + bias, 0.0f);
        Hs[row * HS_STRIDE + oc] = f2bf(h);
      }
    }
  }
  __syncthreads();

#pragma unroll
  for (int nt = 0; nt < 4; ++nt)
#pragma unroll
    for (int mt = 0; mt < 2; ++mt) acc[nt][mt] = (f32x4){0.f, 0.f, 0.f, 0.f};

  // GEMM2: [32 x 256] @ W2^T -> [32 x 256]
  for (int ks = 0; ks < 8; ++ks) {
    const int ko = ks * 32 + quad * 8;
    bf16x8 a0 = *(const bf16x8*)(&Hs[lrow * HS_STRIDE + ko]);
    bf16x8 a1 = *(const bf16x8*)(&Hs[(lrow + 16) * HS_STRIDE + ko]);
#pragma unroll
    for (int nt = 0; nt < 4; ++nt) {
      const int oc = nw + nt * 16 + lrow;
      bf16x8 bf = *(const bf16x8*)(w2b + oc * CMID + ko);
      acc[nt][0] = __builtin_amdgcn_mfma_f32_16x16x32_bf16(a0, bf, acc[nt][0], 0, 0, 0);
      acc[nt][1] = __builtin_amdgcn_mfma_f32_16x16x32_bf16(a1, bf, acc[nt][1], 0, 0, 0);
    }
  }

  // epilogue2: bias + relu + max over 32 samples -> out[b][oc][s]
#pragma unroll
  for (int nt = 0; nt < 4; ++nt) {
    const int oc = nw + nt * 16 + lrow;
    const float bias = b2[oc];
    float v = -3.4e38f;
#pragma unroll
    for (int mt = 0; mt < 2; ++mt) {
      f32x4 a = acc[nt][mt];
      v = fmaxf(v, fmaxf(fmaxf(a[0], a[1]), fmaxf(a[2], a[3])));
    }
    v = fmaxf(v + bias, 0.0f);            // monotone: == max of per-element bias+relu
    v = fmaxf(v, __shfl_xor(v, 16, 64));
    v = fmaxf(v, __shfl_xor(v, 32, 64));
    if (lane < 16) out[((size_t)bb * COUT + oc) * NPOINT + s] = v;
  }
}

extern "C" void kernel_launch(void* const* d_in, const int* in_sizes, int n_in,
                              void* d_out, int out_size, void* d_ws, size_t ws_size,
                              hipStream_t stream) {
  const float* xyz   = (const float*)d_in[0];
  const float* feats = (const float*)d_in[1];
  const float* w1    = (const float*)d_in[2];
  const float* g1    = (const float*)d_in[3];
  const float* be1   = (const float*)d_in[4];
  const float* m1    = (const float*)d_in[5];
  const float* v1    = (const float*)d_in[6];
  const float* w2    = (const float*)d_in[7];
  const float* g2    = (const float*)d_in[8];
  const float* be2   = (const float*)d_in[9];
  const float* m2    = (const float*)d_in[10];
  const float* v2    = (const float*)d_in[11];
  float* out = (float*)d_out;

  char* ws = (char*)d_ws;
  int*   inds = (int*)(ws);              // 1024 ints   -> 4096 B
  int*   idx  = (int*)(ws + 4096);       // 32768 ints  -> 131072 B
  short* w1b  = (short*)(ws + 135168);   // 256*288 bf16 -> 147456 B
  short* w2b  = (short*)(ws + 282624);   // 256*256 bf16 -> 131072 B
  float* b1   = (float*)(ws + 413696);   // 256 f32
  float* b2   = (float*)(ws + 414720);   // 256 f32

  prep_kernel<<<288, 256, 0, stream>>>(w1, g1, be1, m1, v1, w2, g2, be2, m2, v2,
                                       w1b, w2b, b1, b2);
  fps_kernel<<<NB, FPS_T, 0, stream>>>(xyz, inds);
  ballq_kernel<<<256, 256, 0, stream>>>(xyz, inds, idx);
  mlp_kernel<<<NB * NPOINT, 256, 0, stream>>>(xyz, feats, inds, idx, w1b, w2b, b1, b2, out);
}